// Round 6
// baseline (845.306 us; speedup 1.0000x reference)
//
#include <hip/hip_runtime.h>
#include <hip/hip_fp16.h>

#define NPTS 131072   // B*S = 128*1024
#define DIM  256
#define KTOT 512
// hh-only f16 GEMM: score-difference error sigma ~0.018; GAP_T = 0.2 is ~11 sigma.
// All points with approx top-2 gap < GAP_T get an exact re-check (coalesced, vs cT).
#define GAP_T 0.2f

typedef unsigned short u16;
typedef _Float16 half8 __attribute__((ext_vector_type(8)));
typedef float floatx4 __attribute__((ext_vector_type(4)));

// ---------------- ws layout (main path) ----------------
// 0        : c2 double[512]                    (4096)
// 4096     : Ch u16[512*256]                   (262144)
// 528384   : idx int[131072]                   (524288)
// 1052672  : pv1 float[4][131072]              (2097152)   | after combine: offsets int[513], cursors int[512]
// 3149824  : pk1 int[4][131072]                (2097152)
// 5246976  : pv2 float[4][131072]              (2097152)   | after combine: plist int[131072]
// 7344128  : sums float[512*256]               (524288)
// 7868416  : counts int[512]                   (2048)
// 7870464  : flagcnt int[16]                   (64)
// 7870528  : flaglist int[131072]              (524288)
#define WS_MAIN_NEED 8394816u
// out-buffer scratch (rewritten by onehot/ema at the end):
//   Xh u16[NPTS*DIM] at out+0          (64 MB)  — f16 row-major x, read only by gemm
//   cT float[DIM][KTOT] at out+128MB   (512 KB) — transposed centroids, read only by refine

// ---------- c2 in fp64 (fallback path) ----------
__global__ __launch_bounds__(64)
void c2_kernel(const float* __restrict__ c, double* __restrict__ c2) {
  int k = blockIdx.x;
  int lane = threadIdx.x;
  const float* row = c + (size_t)k * DIM;
  double s = 0.0;
#pragma unroll
  for (int r = 0; r < DIM / 64; ++r) {
    float v = row[r * 64 + lane];
    s += (double)v * (double)v;
  }
#pragma unroll
  for (int off = 32; off > 0; off >>= 1) s += __shfl_down(s, off);
  if (lane == 0) c2[k] = s;
}

// ---------- fused centroid prep: c2 (f64) + Ch (f16 row-major) + cT (transpose) ----------
__global__ __launch_bounds__(64)
void prep_c_kernel(const float* __restrict__ c, double* __restrict__ c2,
                   u16* __restrict__ Ch, float* __restrict__ cT) {
  int k = blockIdx.x, lane = threadIdx.x;
  const float* row = c + (size_t)k * DIM;
  float4 v = ((const float4*)row)[lane];   // dims lane*4 .. lane*4+3
  // c2 in f64
  double s = (double)v.x * v.x + (double)v.y * v.y + (double)v.z * v.z + (double)v.w * v.w;
#pragma unroll
  for (int off = 32; off > 0; off >>= 1) s += __shfl_down(s, off);
  if (lane == 0) c2[k] = s;
  // cT column write (scattered; 512 KB total across kernel, L2-absorbed)
  cT[(size_t)(lane * 4 + 0) * KTOT + k] = v.x;
  cT[(size_t)(lane * 4 + 1) * KTOT + k] = v.y;
  cT[(size_t)(lane * 4 + 2) * KTOT + k] = v.z;
  cT[(size_t)(lane * 4 + 3) * KTOT + k] = v.w;
  // Ch: plain row-major f16
  union { _Float16 hh[4]; ushort4 u; } cvt;
  cvt.hh[0] = (_Float16)v.x; cvt.hh[1] = (_Float16)v.y;
  cvt.hh[2] = (_Float16)v.z; cvt.hh[3] = (_Float16)v.w;
  *(ushort4*)(Ch + (size_t)k * DIM + lane * 4) = cvt.u;
}

// ---------- pre-convert x to f16, plain row-major (into out-scratch) ----------
__global__ __launch_bounds__(256)
void convert_x_kernel(const float* __restrict__ x, u16* __restrict__ Xh) {
  int id = blockIdx.x * 256 + threadIdx.x;   // NPTS*32 units
  int n = id >> 5;          // point 0..131071
  int j = id & 31;          // 8-chunk 0..31
  const float4* src = (const float4*)(x + (size_t)n * DIM + j * 8);
  float4 f0 = src[0], f1 = src[1];
  half8 hv;
  hv[0] = (_Float16)f0.x; hv[1] = (_Float16)f0.y; hv[2] = (_Float16)f0.z; hv[3] = (_Float16)f0.w;
  hv[4] = (_Float16)f1.x; hv[5] = (_Float16)f1.y; hv[6] = (_Float16)f1.z; hv[7] = (_Float16)f1.w;
  *(half8*)(Xh + (size_t)n * DIM + j * 8) = hv;
}

// ---------- MFMA f16 GEMM, direct global->register fragments (no LDS, no barriers) ----------
// K=256 is tiny: the LDS staging + vmcnt(0)+barrier cadence was pure overhead.
// Fragments are 16B loads at base+imm offsets; A/B tiles are L1/L2-resident.
__global__ __launch_bounds__(256)
void gemm_topk_kernel(const u16* __restrict__ Xh, const u16* __restrict__ Ch,
                      const double* __restrict__ c2,
                      float* __restrict__ pv1, int* __restrict__ pk1, float* __restrict__ pv2) {
  __shared__ float mv1[128][2], mv2[128][2];
  __shared__ int mk1[128][2];

  const int tid = threadIdx.x;
  const int bx = blockIdx.x;
  // XCD-aware swizzle: the 4 n-blocks sharing an A-tile get equal bx%8 (same XCD
  // under round-robin dispatch) so the A-tile stays in that XCD's L2.
  const int nblk = (bx >> 3) & 3;
  const int mblk = (bx & 7) + ((bx >> 5) << 3);
  const int m0 = mblk * 128, n0 = nblk * 128;
  const int w = tid >> 6, lane = tid & 63;
  const int wm = (w & 1) * 64, wn = (w >> 1) * 64;
  const int lm = lane & 15, quad = lane >> 4;

  // per-thread fragment base pointers (row + quad column base); K offsets are imm
  const u16* pA[4];
  const u16* pB[4];
#pragma unroll
  for (int t = 0; t < 4; ++t) {
    pA[t] = Xh + (size_t)(m0 + wm + t * 16 + lm) * DIM + quad * 8;
    pB[t] = Ch + (size_t)(n0 + wn + t * 16 + lm) * DIM + quad * 8;
  }

  floatx4 acc[4][4] = {};

#pragma unroll
  for (int kc = 0; kc < 4; ++kc) {
#pragma unroll
    for (int s = 0; s < 2; ++s) {
      const int ko = kc * 64 + s * 32;     // compile-time after unroll
      half8 ah[4], bh[4];
#pragma unroll
      for (int t = 0; t < 4; ++t) {
        ah[t] = *(const half8*)(pA[t] + ko);
        bh[t] = *(const half8*)(pB[t] + ko);
      }
#pragma unroll
      for (int mt = 0; mt < 4; ++mt)
#pragma unroll
        for (int nt = 0; nt < 4; ++nt)
          acc[mt][nt] = __builtin_amdgcn_mfma_f32_16x16x32_f16(ah[mt], bh[nt], acc[mt][nt], 0, 0, 0);
    }
  }

  // ---- epilogue: register top-2 per output row ----
  float c2f[4];
#pragma unroll
  for (int nt = 0; nt < 4; ++nt) c2f[nt] = (float)c2[n0 + wn + nt * 16 + lm];

#pragma unroll
  for (int mt = 0; mt < 4; ++mt)
#pragma unroll
    for (int r = 0; r < 4; ++r) {
      float bv = 1e30f, sv = 1e30f;
      int bk = 0;
#pragma unroll
      for (int nt = 0; nt < 4; ++nt) {       // ascending nt = ascending n: tie keeps lower k
        float v = c2f[nt] - 2.0f * acc[mt][nt][r];
        int n = n0 + wn + nt * 16 + lm;
        if (v < bv) { sv = bv; bv = v; bk = n; }
        else if (v < sv) sv = v;
      }
#pragma unroll
      for (int off = 1; off < 16; off <<= 1) {
        float ov = __shfl_xor(bv, off);
        int ok = __shfl_xor(bk, off);
        float osv = __shfl_xor(sv, off);
        if (ov < bv || (ov == bv && ok < bk)) { sv = fminf(bv, osv); bv = ov; bk = ok; }
        else sv = fminf(sv, ov);             // equal-value tie -> sv==bv -> gap 0 -> flagged
      }
      if (lm == 0) {
        int mr = wm + mt * 16 + quad * 4 + r;
        int sl = w >> 1;
        mv1[mr][sl] = bv; mk1[mr][sl] = bk; mv2[mr][sl] = sv;
      }
    }
  __syncthreads();
  if (tid < 128) {
    float bv = mv1[tid][0], sv = mv2[tid][0];
    int bk = mk1[tid][0];
    float ov = mv1[tid][1], osv = mv2[tid][1];
    if (ov < bv) { sv = fminf(bv, osv); bv = ov; bk = mk1[tid][1]; }  // slice0 lower n: tie keeps slice0
    else sv = fminf(sv, ov);
    int m = m0 + tid;
    pv1[(size_t)nblk * NPTS + m] = bv;
    pk1[(size_t)nblk * NPTS + m] = bk;
    pv2[(size_t)nblk * NPTS + m] = sv;
  }
}

// ---------- merge 4 n-block partials -> idx + flag near-ties + histogram ----------
__global__ __launch_bounds__(256)
void combine_kernel(const float* __restrict__ pv1, const int* __restrict__ pk1,
                    const float* __restrict__ pv2, int* __restrict__ idx,
                    int* __restrict__ flagcnt, int* __restrict__ flaglist,
                    int* __restrict__ counts) {
  __shared__ int h[KTOT];
  int t = threadIdx.x;
#pragma unroll
  for (int i = 0; i < KTOT / 256; ++i) h[i * 256 + t] = 0;
  __syncthreads();
  int m = blockIdx.x * 256 + t;
  float bv = 1e30f, sv = 1e30f;
  int bk = 0;
#pragma unroll
  for (int b = 0; b < 4; ++b) {     // ascending b = ascending k: tie keeps lower k
    float v1 = pv1[(size_t)b * NPTS + m];
    int k1 = pk1[(size_t)b * NPTS + m];
    float v2 = pv2[(size_t)b * NPTS + m];
    if (v1 < bv) { sv = fminf(bv, v2); bv = v1; bk = k1; }
    else { sv = fminf(sv, v1); }
  }
  idx[m] = bk;
  atomicAdd(&h[bk], 1);
  if (sv - bv < GAP_T) {
    int p = atomicAdd(flagcnt, 1);
    flaglist[p] = m;
  }
  __syncthreads();
#pragma unroll
  for (int i = 0; i < KTOT / 256; ++i) {
    int v = h[i * 256 + t];
    if (v) atomicAdd(&counts[i * 256 + t], v);
  }
}

// ---------- exact re-check of flagged points, coalesced against cT ----------
__global__ __launch_bounds__(256)
void refine_kernel(const float* __restrict__ x, const float* __restrict__ cT,
                   const double* __restrict__ c2, const int* __restrict__ flagcnt,
                   const int* __restrict__ flaglist, int* __restrict__ idx,
                   int* __restrict__ counts) {
  __shared__ __align__(16) float xs[DIM];
  __shared__ double rv[256];
  __shared__ int rk[256];
  int cnt = *(volatile const int*)flagcnt;
  const int ka = threadIdx.x, kb = threadIdx.x + 256;
  for (int i = blockIdx.x; i < cnt; i += gridDim.x) {
    __syncthreads();
    int m = flaglist[i];
    if (threadIdx.x < 64)
      ((float4*)xs)[threadIdx.x] = ((const float4*)(x + (size_t)m * DIM))[threadIdx.x];
    __syncthreads();
    double da = 0.0, db = 0.0;
#pragma unroll
    for (int dc = 0; dc < 8; ++dc) {
      float fa = 0.0f, fb = 0.0f;
#pragma unroll
      for (int d4 = 0; d4 < 8; ++d4) {
        float4 xv = ((const float4*)xs)[dc * 8 + d4];
        const float* ct0 = cT + (size_t)(dc * 32 + d4 * 4) * KTOT;
        fa = fmaf(xv.x, ct0[ka], fa);            fb = fmaf(xv.x, ct0[kb], fb);
        fa = fmaf(xv.y, ct0[KTOT + ka], fa);     fb = fmaf(xv.y, ct0[KTOT + kb], fb);
        fa = fmaf(xv.z, ct0[2 * KTOT + ka], fa); fb = fmaf(xv.z, ct0[2 * KTOT + kb], fb);
        fa = fmaf(xv.w, ct0[3 * KTOT + ka], fa); fb = fmaf(xv.w, ct0[3 * KTOT + kb], fb);
      }
      da += (double)fa; db += (double)fb;
    }
    double sa = c2[ka] - 2.0 * da, sb = c2[kb] - 2.0 * db;
    double bestv; int bestk;
    if (sa <= sb) { bestv = sa; bestk = ka; }   // tie keeps lower k
    else          { bestv = sb; bestk = kb; }
    rv[threadIdx.x] = bestv; rk[threadIdx.x] = bestk;
    __syncthreads();
    for (int off = 128; off > 0; off >>= 1) {
      if (threadIdx.x < off) {
        double v = rv[threadIdx.x + off]; int kk = rk[threadIdx.x + off];
        if (v < rv[threadIdx.x] || (v == rv[threadIdx.x] && kk < rk[threadIdx.x])) {
          rv[threadIdx.x] = v; rk[threadIdx.x] = kk;
        }
      }
      __syncthreads();
    }
    if (threadIdx.x == 0) {
      int bk = rk[0];
      int old = idx[m];
      if (bk != old) {
        idx[m] = bk;
        atomicSub(&counts[old], 1);
        atomicAdd(&counts[bk], 1);
      }
    }
  }
}

// ---------- one-hot write (plain stores) ----------
__global__ __launch_bounds__(256)
void onehot_kernel(const int* __restrict__ idx, float* __restrict__ out) {
  __shared__ int bk[32];
  int b = blockIdx.x;  // 32 points per block
  if (threadIdx.x < 32) bk[threadIdx.x] = idx[b * 32 + threadIdx.x];
  __syncthreads();
  float4* o = (float4*)(out + (size_t)b * 32 * KTOT);
#pragma unroll
  for (int j = 0; j < 16; ++j) {
    int f4 = j * 256 + threadIdx.x;   // 0..4095
    int p = f4 >> 7;                  // 128 float4 per row
    int n4 = (f4 & 127) * 4;
    int k = bk[p];
    float4 v;
    v.x = (k == n4 + 0) ? 1.0f : 0.0f;
    v.y = (k == n4 + 1) ? 1.0f : 0.0f;
    v.z = (k == n4 + 2) ? 1.0f : 0.0f;
    v.w = (k == n4 + 3) ? 1.0f : 0.0f;
    o[f4] = v;
  }
}

// ================= counting-sort sums pipeline =================
__global__ __launch_bounds__(512)
void scan_kernel(const int* __restrict__ counts, int* __restrict__ offsets,
                 int* __restrict__ cursors) {
  __shared__ int s[KTOT];
  int t = threadIdx.x;
  int mine = counts[t];
  s[t] = mine;
  __syncthreads();
  for (int off = 1; off < KTOT; off <<= 1) {
    int v = (t >= off) ? s[t - off] : 0;
    __syncthreads();
    s[t] += v;
    __syncthreads();
  }
  int excl = s[t] - mine;
  offsets[t] = excl;
  cursors[t] = excl;
  if (t == KTOT - 1) offsets[KTOT] = s[t];
}

__global__ __launch_bounds__(256)
void scatter_kernel(const int* __restrict__ idx, int* __restrict__ cursors,
                    int* __restrict__ plist) {
  int base = blockIdx.x * 1024 + threadIdx.x;
#pragma unroll
  for (int j = 0; j < 4; ++j) {
    int n = base + j * 256;
    int k = idx[n];
    int pos = atomicAdd(&cursors[k], 1);
    plist[pos] = n;
  }
}

// gathersum_flat: skew-proof — every wave owns 32 consecutive sorted positions.
__global__ __launch_bounds__(256)
void gathersum_flat_kernel(const float* __restrict__ x, const int* __restrict__ plist,
                           const int* __restrict__ offsets, float* __restrict__ sums) {
  __shared__ int offs[KTOT + 1];
  for (int t = threadIdx.x; t < KTOT + 1; t += 256) offs[t] = offsets[t];
  __syncthreads();
  const int w = threadIdx.x >> 6, lane = threadIdx.x & 63;
  const int wid = blockIdx.x * 4 + w;   // 4096 waves total
  const int p0 = wid * 32, p1 = p0 + 32;

  int lo = 0, hi = KTOT;
  while (hi - lo > 1) { int mid = (lo + hi) >> 1; if (offs[mid] <= p0) lo = mid; else hi = mid; }
  int k = lo;

  float4 acc = make_float4(0.f, 0.f, 0.f, 0.f);
  bool any = false;
#pragma unroll 4
  for (int i = p0; i < p1; ++i) {
    while (i >= offs[k + 1]) {
      if (any) {
        float* dst = sums + (size_t)k * DIM + lane * 4;
        atomicAdd(dst + 0, acc.x); atomicAdd(dst + 1, acc.y);
        atomicAdd(dst + 2, acc.z); atomicAdd(dst + 3, acc.w);
        acc = make_float4(0.f, 0.f, 0.f, 0.f);
        any = false;
      }
      ++k;
    }
    int pid = plist[i];
    float4 v = ((const float4*)x)[(size_t)pid * 64 + lane];
    acc.x += v.x; acc.y += v.y; acc.z += v.z; acc.w += v.w;
    any = true;
  }
  if (any) {
    float* dst = sums + (size_t)k * DIM + lane * 4;
    atomicAdd(dst + 0, acc.x); atomicAdd(dst + 1, acc.y);
    atomicAdd(dst + 2, acc.z); atomicAdd(dst + 3, acc.w);
  }
}

__global__ __launch_bounds__(256)
void ema_kernel(const float* __restrict__ c, const float* __restrict__ sums,
                const int* __restrict__ counts, float* __restrict__ outc) {
  int k = blockIdx.x;
  int d = threadIdx.x;
  float cnt = (float)counts[k];
  size_t o = (size_t)k * DIM + d;
  float nc = sums[o] / cnt;
  outc[o] = 0.9f * c[o] + 0.1f * nc;
}

// ---------- round-1 ballot sums (fallback path only) ----------
#define GB 4
#define SLICES 8
__global__ __launch_bounds__(256)
void sums_kernel(const float* __restrict__ x, const int* __restrict__ idx,
                 float* __restrict__ sums, int* __restrict__ counts) {
  const int groups = KTOT / GB;
  const int group = blockIdx.x % groups;
  const int slice = blockIdx.x / groups;
  const int kg0 = group * GB;
  const int tid = threadIdx.x;
  const int lane = tid & 63;
  const int w = tid >> 6;
  const int per_slice = NPTS / SLICES;
  const int nbeg = slice * per_slice;

  float4 acc[GB];
  int cnt[GB];
#pragma unroll
  for (int j = 0; j < GB; ++j) { acc[j] = make_float4(0.f, 0.f, 0.f, 0.f); cnt[j] = 0; }

  for (int it = 0; it < per_slice; it += 256) {
    int n = nbeg + it + tid;
    int k = idx[n];
#pragma unroll
    for (int j = 0; j < GB; ++j) {
      unsigned long long m = __ballot(k == kg0 + j);
      while (m) {
        int src = __ffsll((unsigned long long)m) - 1;
        int nn = __shfl(n, src);
        float4 v = ((const float4*)(x + (size_t)nn * DIM))[lane];
        acc[j].x += v.x; acc[j].y += v.y; acc[j].z += v.z; acc[j].w += v.w;
        cnt[j]++;
        m &= (m - 1);
      }
    }
  }

  __shared__ __align__(16) float lacc[4][GB][DIM];
  __shared__ int lcnt[4][GB];
#pragma unroll
  for (int j = 0; j < GB; ++j) ((float4*)&lacc[w][j][0])[lane] = acc[j];
  if (lane == 0) {
#pragma unroll
    for (int j = 0; j < GB; ++j) lcnt[w][j] = cnt[j];
  }
  __syncthreads();
#pragma unroll
  for (int j = 0; j < GB; ++j) {
    float s = lacc[0][j][tid] + lacc[1][j][tid] + lacc[2][j][tid] + lacc[3][j][tid];
    atomicAdd(&sums[(size_t)(kg0 + j) * DIM + tid], s);
  }
  if (tid < GB) {
    int ct = lcnt[0][tid] + lcnt[1][tid] + lcnt[2][tid] + lcnt[3][tid];
    atomicAdd(&counts[kg0 + tid], ct);
  }
}

// ================= round-1 fallback assign (if ws too small) =================
#define MP 64
#define KT 64
#define DT 32
__global__ __launch_bounds__(256, 2)
void assign_kernel_r1(const float* __restrict__ x, const float* __restrict__ c,
                      const double* __restrict__ c2, float* __restrict__ out,
                      int* __restrict__ idx_out) {
  __shared__ __align__(16) float xs[DIM * MP];
  __shared__ __align__(16) float cs[DT * KT];
  const int tid = threadIdx.x;
  const int p0 = blockIdx.x * MP;
  const int tp = tid & 15;
  const int tk = tid >> 4;
  {
    const int p = tid >> 2;
    const int dg = tid & 3;
    const float4* x4 = (const float4*)(x + (size_t)(p0 + p) * DIM);
#pragma unroll
    for (int r = 0; r < 16; ++r) {
      int d4 = r * 4 + dg;
      float4 v = x4[d4];
      int dbase = d4 * 4;
      xs[(dbase + 0) * MP + p] = v.x;
      xs[(dbase + 1) * MP + p] = v.y;
      xs[(dbase + 2) * MP + p] = v.z;
      xs[(dbase + 3) * MP + p] = v.w;
    }
  }
  double best[4]; int bestk[4];
#pragma unroll
  for (int i = 0; i < 4; ++i) { best[i] = 1e300; bestk[i] = 0; }
  for (int kc = 0; kc < KTOT / KT; ++kc) {
    const int k0 = kc * KT;
    double dacc[4][4];
#pragma unroll
    for (int i = 0; i < 4; ++i)
#pragma unroll
      for (int j = 0; j < 4; ++j) dacc[i][j] = 0.0;
    for (int dc = 0; dc < DIM / DT; ++dc) {
      __syncthreads();
      {
        const int kl = tid >> 2;
        const int dg = tid & 3;
        const float4* c4 = (const float4*)(c + (size_t)(k0 + kl) * DIM + dc * DT);
#pragma unroll
        for (int h = 0; h < 2; ++h) {
          int dq = h * 4 + dg;
          float4 v = c4[dq];
          int dbase = dq * 4;
          cs[(dbase + 0) * KT + kl] = v.x;
          cs[(dbase + 1) * KT + kl] = v.y;
          cs[(dbase + 2) * KT + kl] = v.z;
          cs[(dbase + 3) * KT + kl] = v.w;
        }
      }
      __syncthreads();
      float acc[4][4];
#pragma unroll
      for (int i = 0; i < 4; ++i)
#pragma unroll
        for (int j = 0; j < 4; ++j) acc[i][j] = 0.0f;
#pragma unroll
      for (int d = 0; d < DT; ++d) {
        float4 xv = ((const float4*)(xs + (size_t)(dc * DT + d) * MP))[tp];
        float4 cv = ((const float4*)(cs + (size_t)d * KT))[tk];
        float xa[4] = {xv.x, xv.y, xv.z, xv.w};
        float ca[4] = {cv.x, cv.y, cv.z, cv.w};
#pragma unroll
        for (int i = 0; i < 4; ++i)
#pragma unroll
          for (int j = 0; j < 4; ++j) acc[i][j] = fmaf(xa[i], ca[j], acc[i][j]);
      }
#pragma unroll
      for (int i = 0; i < 4; ++i)
#pragma unroll
        for (int j = 0; j < 4; ++j) dacc[i][j] += (double)acc[i][j];
    }
#pragma unroll
    for (int j = 0; j < 4; ++j) {
      int k = k0 + tk * 4 + j;
      double c2v = c2[k];
#pragma unroll
      for (int i = 0; i < 4; ++i) {
        double s = c2v - 2.0 * dacc[i][j];
        if (s < best[i]) { best[i] = s; bestk[i] = k; }
      }
    }
  }
  __syncthreads();
  double* redv = (double*)cs;
  int* redk = (int*)xs;
  int* bk = (int*)xs + 1024;
#pragma unroll
  for (int i = 0; i < 4; ++i) {
    int p = tp * 4 + i;
    redv[tk * MP + p] = best[i];
    redk[tk * MP + p] = bestk[i];
  }
  __syncthreads();
  if (tid < MP) {
    int p = tid;
    double bv = redv[p]; int bkk = redk[p];
#pragma unroll
    for (int t = 1; t < 16; ++t) {
      double v = redv[t * MP + p]; int kk = redk[t * MP + p];
      if (v < bv || (v == bv && kk < bkk)) { bv = v; bkk = kk; }
    }
    bk[p] = bkk;
    idx_out[p0 + p] = bkk;
  }
  __syncthreads();
  float* orow = out + (size_t)p0 * KTOT;
  for (int l = tid; l < MP * KTOT; l += 256) {
    int p = l >> 9;
    int k = l & (KTOT - 1);
    orow[l] = (k == bk[p]) ? 1.0f : 0.0f;
  }
}

extern "C" void kernel_launch(void* const* d_in, const int* in_sizes, int n_in,
                              void* d_out, int out_size, void* d_ws, size_t ws_size,
                              hipStream_t stream) {
  const float* x = (const float*)d_in[0];
  const float* c = (const float*)d_in[1];
  float* out = (float*)d_out;
  float* outc = out + (size_t)NPTS * KTOT;

  char* ws = (char*)d_ws;

  if (ws_size >= WS_MAIN_NEED) {
    double* c2   = (double*)(ws + 0);
    u16* Ch      = (u16*)(ws + 4096);
    int* idx     = (int*)(ws + 528384);
    float* pv1   = (float*)(ws + 1052672);
    int* pk1     = (int*)(ws + 3149824);
    float* pv2   = (float*)(ws + 5246976);
    float* sums  = (float*)(ws + 7344128);
    int* counts  = (int*)(ws + 7868416);
    int* flagcnt = (int*)(ws + 7870464);
    int* flaglist= (int*)(ws + 7870528);
    // overlays (dead after combine):
    int* offsets = (int*)(ws + 1052672);            // 513 ints, over pv1
    int* cursors = (int*)(ws + 1052672 + 4096);     // 512 ints, over pv1
    int* plist   = (int*)(ws + 5246976);            // 131072 ints, over pv2
    // out-buffer scratch (onehot/ema rewrite out afterwards):
    u16* Xh      = (u16*)out;                               // 64 MB
    float* cT    = (float*)((char*)out + 134217728);        // 512 KB

    hipMemsetAsync(sums, 0, (size_t)(KTOT * DIM + KTOT) * 4, stream);  // sums + counts
    hipMemsetAsync(flagcnt, 0, 64, stream);
    prep_c_kernel<<<KTOT, 64, 0, stream>>>(c, c2, Ch, cT);
    convert_x_kernel<<<NPTS * 32 / 256, 256, 0, stream>>>(x, Xh);
    gemm_topk_kernel<<<4096, 256, 0, stream>>>(Xh, Ch, c2, pv1, pk1, pv2);
    combine_kernel<<<NPTS / 256, 256, 0, stream>>>(pv1, pk1, pv2, idx, flagcnt, flaglist, counts);
    refine_kernel<<<1024, 256, 0, stream>>>(x, cT, c2, flagcnt, flaglist, idx, counts);
    onehot_kernel<<<NPTS / 32, 256, 0, stream>>>(idx, out);
    scan_kernel<<<1, 512, 0, stream>>>(counts, offsets, cursors);
    scatter_kernel<<<NPTS / 1024, 256, 0, stream>>>(idx, cursors, plist);
    gathersum_flat_kernel<<<NPTS / 32 / 4, 256, 0, stream>>>(x, plist, offsets, sums);
    ema_kernel<<<KTOT, DIM, 0, stream>>>(c, sums, counts, outc);
  } else {
    // round-1 fallback (ws >= 1.05 MB proven)
    double* c2  = (double*)ws;
    int* idx    = (int*)(ws + 4096);
    float* sums = (float*)(ws + 4096 + 524288);
    int* counts = (int*)(ws + 4096 + 524288 + 524288);
    hipMemsetAsync(sums, 0, (size_t)(KTOT * DIM + KTOT) * 4, stream);
    c2_kernel<<<KTOT, 64, 0, stream>>>(c, c2);
    assign_kernel_r1<<<NPTS / MP, 256, 0, stream>>>(x, c, c2, out, idx);
    sums_kernel<<<(KTOT / GB) * SLICES, 256, 0, stream>>>(x, idx, sums, counts);
    ema_kernel<<<KTOT, DIM, 0, stream>>>(c, sums, counts, outc);
  }
}

// Round 7
// 830.023 us; speedup vs baseline: 1.0184x; 1.0184x over previous
//
#include <hip/hip_runtime.h>
#include <hip/hip_fp16.h>

#define NPTS 131072   // B*S = 128*1024
#define DIM  256
#define KTOT 512
// f16 GEMM score error empirically <= ~0.1 (GAP 0.2 full-rescan rounds passed).
// Pair-check when exactly 2 candidates within GAP_FULL and gap < GAP_PAIR;
// full exact scan when >=3 candidates within GAP_FULL of the best.
#define GAP_PAIR 0.2f
#define GAP_FULL 0.4f

typedef unsigned short u16;
typedef _Float16 half8 __attribute__((ext_vector_type(8)));
typedef float floatx4 __attribute__((ext_vector_type(4)));

union F16U { _Float16 f; unsigned short u; };

// ---------------- ws layout (main path) ----------------
// 0        : c2 double[512]                    (4096)
// 4096     : Ch u16[512*256]                   (262144)
// 528384   : idx int[131072]                   (524288)
// 1052672  : pv1 float[4][131072]              (2097152)   | after combine: offsets int[513], cursors int[512]
// 3149824  : pkk int[4][131072]                (2097152)
// 5246976  : pgg uint[4][131072]               (2097152)   | after combine: plist int[131072]
// 7344128  : sums float[512*256]               (524288)
// 7868416  : counts int[512]                   (2048)
// 7870464  : flagcnt int[16]  ([0]=full,[1]=pair)  (64)
// 7870528  : flaglist int[131072]: full[0..32767], pairm[32768..], pairkk[65536..]
#define WS_MAIN_NEED 8394816u
// out-buffer scratch (rewritten by onehot at the end):
//   cT float[DIM][KTOT] at out+128MB   (512 KB) — transposed centroids, read only by full_refine

// ---------- shared helpers ----------
__device__ __forceinline__ void ins2(float v, int k, float& B, int& KB, float& S, int& KS) {
  if (v < B || (v == B && k < KB)) { S = B; KS = KB; B = v; KB = k; }
  else if (v < S || (v == S && k < KS)) { S = v; KS = k; }
}

// ---------- c2 in fp64 (fallback path) ----------
__global__ __launch_bounds__(64)
void c2_kernel(const float* __restrict__ c, double* __restrict__ c2) {
  int k = blockIdx.x;
  int lane = threadIdx.x;
  const float* row = c + (size_t)k * DIM;
  double s = 0.0;
#pragma unroll
  for (int r = 0; r < DIM / 64; ++r) {
    float v = row[r * 64 + lane];
    s += (double)v * (double)v;
  }
#pragma unroll
  for (int off = 32; off > 0; off >>= 1) s += __shfl_down(s, off);
  if (lane == 0) c2[k] = s;
}

// ---------- fused centroid prep: c2 (f64) + Ch (f16 swizzled) + cT (transpose) ----------
__global__ __launch_bounds__(64)
void prep_c_kernel(const float* __restrict__ c, double* __restrict__ c2,
                   u16* __restrict__ Ch, float* __restrict__ cT) {
  int k = blockIdx.x, lane = threadIdx.x;
  const float* row = c + (size_t)k * DIM;
  float4 v = ((const float4*)row)[lane];   // dims lane*4 .. lane*4+3
  double s = (double)v.x * v.x + (double)v.y * v.y + (double)v.z * v.z + (double)v.w * v.w;
#pragma unroll
  for (int off = 32; off > 0; off >>= 1) s += __shfl_down(s, off);
  if (lane == 0) c2[k] = s;
  cT[(size_t)(lane * 4 + 0) * KTOT + k] = v.x;
  cT[(size_t)(lane * 4 + 1) * KTOT + k] = v.y;
  cT[(size_t)(lane * 4 + 2) * KTOT + k] = v.z;
  cT[(size_t)(lane * 4 + 3) * KTOT + k] = v.w;
  // Ch swizzled: chunk cg = lane>>1, half h = lane&1 covers dims lane*4..+3
  int cg = lane >> 1, h = lane & 1;
  int kc = cg >> 3, cc = cg & 7;
  union { _Float16 hh[4]; ushort4 u; } cvt;
  cvt.hh[0] = (_Float16)v.x; cvt.hh[1] = (_Float16)v.y;
  cvt.hh[2] = (_Float16)v.z; cvt.hh[3] = (_Float16)v.w;
  *(ushort4*)(Ch + (size_t)k * DIM + kc * 64 + (size_t)(cc ^ (k & 7)) * 8 + h * 4) = cvt.u;
}

// ---------- MFMA f16 GEMM (r3-proven staging) + top-2-kv + candidate-count epilogue ----------
__device__ __forceinline__ void load_lds16(const void* g, void* l) {
  __builtin_amdgcn_global_load_lds((const __attribute__((address_space(1))) void*)g,
                                   (__attribute__((address_space(3))) void*)l, 16, 0, 0);
}

__global__ __launch_bounds__(256)
void gemm_topk_kernel(const float* __restrict__ x, const u16* __restrict__ Ch,
                      const double* __restrict__ c2,
                      float* __restrict__ pv1, int* __restrict__ pkk, unsigned* __restrict__ pgg) {
  __shared__ __align__(16) u16 Ah[128 * 64];
  __shared__ __align__(16) u16 Bh[128 * 64];
  __shared__ float mb[128][2], msv[128][2], mbf[128];
  __shared__ int mkb[128][2], mks[128][2], scnt[128][2];

  const int tid = threadIdx.x;
  const int bx = blockIdx.x;
  const int nblk = (bx >> 3) & 3;
  const int mblk = (bx & 7) + ((bx >> 5) << 3);
  const int m0 = mblk * 128, n0 = nblk * 128;
  const int w = tid >> 6, lane = tid & 63;
  const int wm = (w & 1) * 64, wn = (w >> 1) * 64;
  const int lm = lane & 15, quad = lane >> 4;

  floatx4 acc[4][4] = {};

  for (int kc = 0; kc < 4; ++kc) {
    const int k0 = kc * 64;
    __syncthreads();
#pragma unroll
    for (int i = 0; i < 4; ++i) {
      int s = i * 256 + tid;
      int row = s >> 3, pos = s & 7;
      size_t go = (size_t)(n0 + row) * DIM + k0 + pos * 8;
      load_lds16(Ch + go, Bh + (size_t)s * 8);
    }
#pragma unroll
    for (int i = 0; i < 4; ++i) {
      int s = i * 256 + tid;
      int row = s >> 3, kg = s & 7;
      const float4* gx = (const float4*)(x + (size_t)(m0 + row) * DIM + k0 + kg * 8);
      float4 f0 = gx[0], f1 = gx[1];
      float fv[8] = {f0.x, f0.y, f0.z, f0.w, f1.x, f1.y, f1.z, f1.w};
      half8 hv;
#pragma unroll
      for (int e = 0; e < 8; ++e) hv[e] = (_Float16)fv[e];
      int pos = kg ^ (row & 7);
      *(half8*)(Ah + (size_t)row * 64 + pos * 8) = hv;
    }
    __syncthreads();

#pragma unroll
    for (int s = 0; s < 2; ++s) {
      half8 ah[4], bh[4];
#pragma unroll
      for (int t = 0; t < 4; ++t) {
        int m = wm + t * 16 + lm;
        int pa = ((s * 4 + quad) ^ (m & 7)) * 8;
        ah[t] = *(const half8*)(Ah + (size_t)m * 64 + pa);
        int n = wn + t * 16 + lm;
        int pb = ((s * 4 + quad) ^ (n & 7)) * 8;
        bh[t] = *(const half8*)(Bh + (size_t)n * 64 + pb);
      }
#pragma unroll
      for (int mt = 0; mt < 4; ++mt)
#pragma unroll
        for (int nt = 0; nt < 4; ++nt)
          acc[mt][nt] = __builtin_amdgcn_mfma_f32_16x16x32_f16(ah[mt], bh[nt], acc[mt][nt], 0, 0, 0);
    }
  }

  float c2f[4];
#pragma unroll
  for (int nt = 0; nt < 4; ++nt) c2f[nt] = (float)c2[n0 + wn + nt * 16 + lm];

  // ---- phase 1: top-2 with keys (kv-butterfly over the 16 lm lanes) ----
  __syncthreads();
#pragma unroll
  for (int mt = 0; mt < 4; ++mt)
#pragma unroll
    for (int r = 0; r < 4; ++r) {
      float bv = 1e30f, sv = 1e30f;
      int bk = 0x7fffffff, sk = 0x7fffffff;
#pragma unroll
      for (int nt = 0; nt < 4; ++nt) {
        float v = c2f[nt] - 2.0f * acc[mt][nt][r];
        int n = n0 + wn + nt * 16 + lm;
        if (v < bv || (v == bv && n < bk)) { sv = bv; sk = bk; bv = v; bk = n; }
        else if (v < sv || (v == sv && n < sk)) { sv = v; sk = n; }
      }
#pragma unroll
      for (int off = 1; off < 16; off <<= 1) {
        float ov = __shfl_xor(bv, off), osv = __shfl_xor(sv, off);
        int ok = __shfl_xor(bk, off), osk = __shfl_xor(sk, off);
        if (ov < bv || (ov == bv && ok < bk)) {
          if (bv < osv || (bv == osv && bk < osk)) { sv = bv; sk = bk; }
          else { sv = osv; sk = osk; }
          bv = ov; bk = ok;
        } else if (ov < sv || (ov == sv && ok < sk)) { sv = ov; sk = ok; }
      }
      if (lm == 0) {
        int mr = wm + mt * 16 + quad * 4 + r;
        int sl = w >> 1;
        mb[mr][sl] = bv; mkb[mr][sl] = bk; msv[mr][sl] = sv; mks[mr][sl] = sk;
      }
    }
  __syncthreads();
  // cross-slice merge -> per-row (B,KB,S,KS); stash in slice0 slots + broadcast B
  if (tid < 128) {
    float B = mb[tid][0], S = msv[tid][0];
    int KB = mkb[tid][0], KS = mks[tid][0];
    ins2(mb[tid][1], mkb[tid][1], B, KB, S, KS);
    ins2(msv[tid][1], mks[tid][1], B, KB, S, KS);
    mb[tid][0] = B; mkb[tid][0] = KB; msv[tid][0] = S; mks[tid][0] = KS;
    mbf[tid] = B;
  }
  __syncthreads();
  // ---- phase 2: count candidates within GAP_FULL of row best ----
#pragma unroll
  for (int mt = 0; mt < 4; ++mt)
#pragma unroll
    for (int r = 0; r < 4; ++r) {
      int mr = wm + mt * 16 + quad * 4 + r;
      float thr = mbf[mr] + GAP_FULL;
      int cnt = 0;
#pragma unroll
      for (int nt = 0; nt < 4; ++nt)
        cnt += (c2f[nt] - 2.0f * acc[mt][nt][r] < thr) ? 1 : 0;
#pragma unroll
      for (int off = 1; off < 16; off <<= 1) cnt += __shfl_xor(cnt, off);
      if (lm == 0) scnt[mr][w >> 1] = cnt;
    }
  __syncthreads();
  if (tid < 128) {
    float B = mb[tid][0], S = msv[tid][0];
    int KB = mkb[tid][0], KS = mks[tid][0];
    int C = scnt[tid][0] + scnt[tid][1];
    int m = m0 + tid;
    F16U cv; cv.f = (_Float16)(S - B);
    pv1[(size_t)nblk * NPTS + m] = B;
    pkk[(size_t)nblk * NPTS + m] = KB | (KS << 16);
    pgg[(size_t)nblk * NPTS + m] = (unsigned)cv.u | ((unsigned)C << 16);
  }
}

// ---------- merge 4 n-block partials -> idx + hist + pair/full flag lists ----------
__global__ __launch_bounds__(256)
void combine_kernel(const float* __restrict__ pv1, const int* __restrict__ pkk,
                    const unsigned* __restrict__ pgg, int* __restrict__ idx,
                    int* __restrict__ flagcnt, int* __restrict__ flaglist,
                    int* __restrict__ counts) {
  __shared__ int h[KTOT];
  int t = threadIdx.x;
#pragma unroll
  for (int i = 0; i < KTOT / 256; ++i) h[i * 256 + t] = 0;
  __syncthreads();
  int m = blockIdx.x * 256 + t;
  float B = 1e30f, S = 1e30f;
  int KB = 0x7fffffff, KS = 0x7fffffff;
  float bb[4]; int cc[4];
#pragma unroll
  for (int b = 0; b < 4; ++b) {
    float bv = pv1[(size_t)b * NPTS + m];
    int kk = pkk[(size_t)b * NPTS + m];
    unsigned gg = pgg[(size_t)b * NPTS + m];
    int kb_ = kk & 0xffff, ks_ = (kk >> 16) & 0xffff;
    F16U cv; cv.u = (unsigned short)(gg & 0xffffu);
    float sv = bv + (float)cv.f;
    bb[b] = bv; cc[b] = (int)(gg >> 16);
    ins2(bv, kb_, B, KB, S, KS);
    ins2(sv, ks_, B, KB, S, KS);
  }
  idx[m] = KB;
  atomicAdd(&h[KB], 1);
  int tot = 0;
#pragma unroll
  for (int b = 0; b < 4; ++b)
    if (bb[b] < B + GAP_FULL) tot += cc[b];
  if (tot >= 3) {
    int p = atomicAdd(&flagcnt[0], 1);
    if (p < 32768) flaglist[p] = m;                       // full exact scan
  } else if (tot == 2 && (S - B) < GAP_PAIR) {
    int p = atomicAdd(&flagcnt[1], 1);
    if (p < 32768) {
      flaglist[32768 + p] = m;                            // pair check
      flaglist[65536 + p] = KB | (KS << 16);
    }
  }
  __syncthreads();
#pragma unroll
  for (int i = 0; i < KTOT / 256; ++i) {
    int v = h[i * 256 + t];
    if (v) atomicAdd(&counts[i * 256 + t], v);
  }
}

// ---------- exact f64 check of the two candidates (one wave per point) ----------
__global__ __launch_bounds__(256)
void pair_refine_kernel(const float* __restrict__ x, const float* __restrict__ c,
                        const double* __restrict__ c2, const int* __restrict__ flagcnt,
                        const int* __restrict__ flaglist, int* __restrict__ idx,
                        int* __restrict__ counts) {
  int cnt = *(volatile const int*)(flagcnt + 1);
  const int w = threadIdx.x >> 6, lane = threadIdx.x & 63;
  for (int e = blockIdx.x * 4 + w; e < cnt; e += gridDim.x * 4) {
    int m = flaglist[32768 + e];
    int kk = flaglist[65536 + e];
    int ka = kk & 0xffff, kb = (kk >> 16) & 0xffff;
    float4 xv = ((const float4*)(x + (size_t)m * DIM))[lane];
    float4 av = ((const float4*)(c + (size_t)ka * DIM))[lane];
    float4 bv = ((const float4*)(c + (size_t)kb * DIM))[lane];
    float fa = fmaf(xv.x, av.x, fmaf(xv.y, av.y, fmaf(xv.z, av.z, xv.w * av.w)));
    float fb = fmaf(xv.x, bv.x, fmaf(xv.y, bv.y, fmaf(xv.z, bv.z, xv.w * bv.w)));
    double da = (double)fa, db = (double)fb;
#pragma unroll
    for (int off = 32; off > 0; off >>= 1) {
      da += __shfl_down(da, off);
      db += __shfl_down(db, off);
    }
    if (lane == 0) {
      double sa = c2[ka] - 2.0 * da, sb = c2[kb] - 2.0 * db;
      int wk = (sb < sa || (sb == sa && kb < ka)) ? kb : ka;
      if (wk != ka) {      // idx[m] == ka (tentative best)
        idx[m] = wk;
        atomicSub(&counts[ka], 1);
        atomicAdd(&counts[wk], 1);
      }
    }
  }
}

// ---------- full exact scan of rare >=3-candidate points (coalesced vs cT) ----------
__global__ __launch_bounds__(256)
void full_refine_kernel(const float* __restrict__ x, const float* __restrict__ cT,
                        const double* __restrict__ c2, const int* __restrict__ flagcnt,
                        const int* __restrict__ flaglist, int* __restrict__ idx,
                        int* __restrict__ counts) {
  __shared__ __align__(16) float xs[DIM];
  __shared__ double rv[256];
  __shared__ int rk[256];
  int cnt = *(volatile const int*)flagcnt;
  const int ka = threadIdx.x, kb = threadIdx.x + 256;
  for (int i = blockIdx.x; i < cnt; i += gridDim.x) {
    __syncthreads();
    int m = flaglist[i];
    if (threadIdx.x < 64)
      ((float4*)xs)[threadIdx.x] = ((const float4*)(x + (size_t)m * DIM))[threadIdx.x];
    __syncthreads();
    double da = 0.0, db = 0.0;
#pragma unroll
    for (int dc = 0; dc < 8; ++dc) {
      float fa = 0.0f, fb = 0.0f;
#pragma unroll
      for (int d4 = 0; d4 < 8; ++d4) {
        float4 xv = ((const float4*)xs)[dc * 8 + d4];
        const float* ct0 = cT + (size_t)(dc * 32 + d4 * 4) * KTOT;
        fa = fmaf(xv.x, ct0[ka], fa);            fb = fmaf(xv.x, ct0[kb], fb);
        fa = fmaf(xv.y, ct0[KTOT + ka], fa);     fb = fmaf(xv.y, ct0[KTOT + kb], fb);
        fa = fmaf(xv.z, ct0[2 * KTOT + ka], fa); fb = fmaf(xv.z, ct0[2 * KTOT + kb], fb);
        fa = fmaf(xv.w, ct0[3 * KTOT + ka], fa); fb = fmaf(xv.w, ct0[3 * KTOT + kb], fb);
      }
      da += (double)fa; db += (double)fb;
    }
    double sa = c2[ka] - 2.0 * da, sb = c2[kb] - 2.0 * db;
    double bestv; int bestk;
    if (sa <= sb) { bestv = sa; bestk = ka; }
    else          { bestv = sb; bestk = kb; }
    rv[threadIdx.x] = bestv; rk[threadIdx.x] = bestk;
    __syncthreads();
    for (int off = 128; off > 0; off >>= 1) {
      if (threadIdx.x < off) {
        double v = rv[threadIdx.x + off]; int kk = rk[threadIdx.x + off];
        if (v < rv[threadIdx.x] || (v == rv[threadIdx.x] && kk < rk[threadIdx.x])) {
          rv[threadIdx.x] = v; rk[threadIdx.x] = kk;
        }
      }
      __syncthreads();
    }
    if (threadIdx.x == 0) {
      int bk = rk[0];
      int old = idx[m];
      if (bk != old) {
        idx[m] = bk;
        atomicSub(&counts[old], 1);
        atomicAdd(&counts[bk], 1);
      }
    }
  }
}

// ---------- one-hot write ----------
__global__ __launch_bounds__(256)
void onehot_kernel(const int* __restrict__ idx, float* __restrict__ out) {
  __shared__ int bk[32];
  int b = blockIdx.x;
  if (threadIdx.x < 32) bk[threadIdx.x] = idx[b * 32 + threadIdx.x];
  __syncthreads();
  float4* o = (float4*)(out + (size_t)b * 32 * KTOT);
#pragma unroll
  for (int j = 0; j < 16; ++j) {
    int f4 = j * 256 + threadIdx.x;
    int p = f4 >> 7;
    int n4 = (f4 & 127) * 4;
    int k = bk[p];
    float4 v;
    v.x = (k == n4 + 0) ? 1.0f : 0.0f;
    v.y = (k == n4 + 1) ? 1.0f : 0.0f;
    v.z = (k == n4 + 2) ? 1.0f : 0.0f;
    v.w = (k == n4 + 3) ? 1.0f : 0.0f;
    o[f4] = v;
  }
}

// ================= counting-sort sums pipeline =================
__global__ __launch_bounds__(512)
void scan_kernel(const int* __restrict__ counts, int* __restrict__ offsets,
                 int* __restrict__ cursors) {
  __shared__ int s[KTOT];
  int t = threadIdx.x;
  int mine = counts[t];
  s[t] = mine;
  __syncthreads();
  for (int off = 1; off < KTOT; off <<= 1) {
    int v = (t >= off) ? s[t - off] : 0;
    __syncthreads();
    s[t] += v;
    __syncthreads();
  }
  int excl = s[t] - mine;
  offsets[t] = excl;
  cursors[t] = excl;
  if (t == KTOT - 1) offsets[KTOT] = s[t];
}

__global__ __launch_bounds__(256)
void scatter_kernel(const int* __restrict__ idx, int* __restrict__ cursors,
                    int* __restrict__ plist) {
  int base = blockIdx.x * 1024 + threadIdx.x;
#pragma unroll
  for (int j = 0; j < 4; ++j) {
    int n = base + j * 256;
    int k = idx[n];
    int pos = atomicAdd(&cursors[k], 1);
    plist[pos] = n;
  }
}

// gathersum_flat: skew-proof — every wave owns 32 consecutive sorted positions.
__global__ __launch_bounds__(256)
void gathersum_flat_kernel(const float* __restrict__ x, const int* __restrict__ plist,
                           const int* __restrict__ offsets, float* __restrict__ sums) {
  __shared__ int offs[KTOT + 1];
  for (int t = threadIdx.x; t < KTOT + 1; t += 256) offs[t] = offsets[t];
  __syncthreads();
  const int w = threadIdx.x >> 6, lane = threadIdx.x & 63;
  const int wid = blockIdx.x * 4 + w;
  const int p0 = wid * 32, p1 = p0 + 32;

  int lo = 0, hi = KTOT;
  while (hi - lo > 1) { int mid = (lo + hi) >> 1; if (offs[mid] <= p0) lo = mid; else hi = mid; }
  int k = lo;

  float4 acc = make_float4(0.f, 0.f, 0.f, 0.f);
  bool any = false;
#pragma unroll 4
  for (int i = p0; i < p1; ++i) {
    while (i >= offs[k + 1]) {
      if (any) {
        float* dst = sums + (size_t)k * DIM + lane * 4;
        atomicAdd(dst + 0, acc.x); atomicAdd(dst + 1, acc.y);
        atomicAdd(dst + 2, acc.z); atomicAdd(dst + 3, acc.w);
        acc = make_float4(0.f, 0.f, 0.f, 0.f);
        any = false;
      }
      ++k;
    }
    int pid = plist[i];
    float4 v = ((const float4*)x)[(size_t)pid * 64 + lane];
    acc.x += v.x; acc.y += v.y; acc.z += v.z; acc.w += v.w;
    any = true;
  }
  if (any) {
    float* dst = sums + (size_t)k * DIM + lane * 4;
    atomicAdd(dst + 0, acc.x); atomicAdd(dst + 1, acc.y);
    atomicAdd(dst + 2, acc.z); atomicAdd(dst + 3, acc.w);
  }
}

__global__ __launch_bounds__(256)
void ema_kernel(const float* __restrict__ c, const float* __restrict__ sums,
                const int* __restrict__ counts, float* __restrict__ outc) {
  int k = blockIdx.x;
  int d = threadIdx.x;
  float cnt = (float)counts[k];
  size_t o = (size_t)k * DIM + d;
  float nc = sums[o] / cnt;
  outc[o] = 0.9f * c[o] + 0.1f * nc;
}

// ---------- round-1 ballot sums (fallback path only) ----------
#define GB 4
#define SLICES 8
__global__ __launch_bounds__(256)
void sums_kernel(const float* __restrict__ x, const int* __restrict__ idx,
                 float* __restrict__ sums, int* __restrict__ counts) {
  const int groups = KTOT / GB;
  const int group = blockIdx.x % groups;
  const int slice = blockIdx.x / groups;
  const int kg0 = group * GB;
  const int tid = threadIdx.x;
  const int lane = tid & 63;
  const int w = tid >> 6;
  const int per_slice = NPTS / SLICES;
  const int nbeg = slice * per_slice;

  float4 acc[GB];
  int cnt[GB];
#pragma unroll
  for (int j = 0; j < GB; ++j) { acc[j] = make_float4(0.f, 0.f, 0.f, 0.f); cnt[j] = 0; }

  for (int it = 0; it < per_slice; it += 256) {
    int n = nbeg + it + tid;
    int k = idx[n];
#pragma unroll
    for (int j = 0; j < GB; ++j) {
      unsigned long long m = __ballot(k == kg0 + j);
      while (m) {
        int src = __ffsll((unsigned long long)m) - 1;
        int nn = __shfl(n, src);
        float4 v = ((const float4*)(x + (size_t)nn * DIM))[lane];
        acc[j].x += v.x; acc[j].y += v.y; acc[j].z += v.z; acc[j].w += v.w;
        cnt[j]++;
        m &= (m - 1);
      }
    }
  }

  __shared__ __align__(16) float lacc[4][GB][DIM];
  __shared__ int lcnt[4][GB];
#pragma unroll
  for (int j = 0; j < GB; ++j) ((float4*)&lacc[w][j][0])[lane] = acc[j];
  if (lane == 0) {
#pragma unroll
    for (int j = 0; j < GB; ++j) lcnt[w][j] = cnt[j];
  }
  __syncthreads();
#pragma unroll
  for (int j = 0; j < GB; ++j) {
    float s = lacc[0][j][tid] + lacc[1][j][tid] + lacc[2][j][tid] + lacc[3][j][tid];
    atomicAdd(&sums[(size_t)(kg0 + j) * DIM + tid], s);
  }
  if (tid < GB) {
    int ct = lcnt[0][tid] + lcnt[1][tid] + lcnt[2][tid] + lcnt[3][tid];
    atomicAdd(&counts[kg0 + tid], ct);
  }
}

// ================= round-1 fallback assign (if ws too small) =================
#define MP 64
#define KT 64
#define DT 32
__global__ __launch_bounds__(256, 2)
void assign_kernel_r1(const float* __restrict__ x, const float* __restrict__ c,
                      const double* __restrict__ c2, float* __restrict__ out,
                      int* __restrict__ idx_out) {
  __shared__ __align__(16) float xs[DIM * MP];
  __shared__ __align__(16) float cs[DT * KT];
  const int tid = threadIdx.x;
  const int p0 = blockIdx.x * MP;
  const int tp = tid & 15;
  const int tk = tid >> 4;
  {
    const int p = tid >> 2;
    const int dg = tid & 3;
    const float4* x4 = (const float4*)(x + (size_t)(p0 + p) * DIM);
#pragma unroll
    for (int r = 0; r < 16; ++r) {
      int d4 = r * 4 + dg;
      float4 v = x4[d4];
      int dbase = d4 * 4;
      xs[(dbase + 0) * MP + p] = v.x;
      xs[(dbase + 1) * MP + p] = v.y;
      xs[(dbase + 2) * MP + p] = v.z;
      xs[(dbase + 3) * MP + p] = v.w;
    }
  }
  double best[4]; int bestk[4];
#pragma unroll
  for (int i = 0; i < 4; ++i) { best[i] = 1e300; bestk[i] = 0; }
  for (int kc = 0; kc < KTOT / KT; ++kc) {
    const int k0 = kc * KT;
    double dacc[4][4];
#pragma unroll
    for (int i = 0; i < 4; ++i)
#pragma unroll
      for (int j = 0; j < 4; ++j) dacc[i][j] = 0.0;
    for (int dc = 0; dc < DIM / DT; ++dc) {
      __syncthreads();
      {
        const int kl = tid >> 2;
        const int dg = tid & 3;
        const float4* c4 = (const float4*)(c + (size_t)(k0 + kl) * DIM + dc * DT);
#pragma unroll
        for (int h = 0; h < 2; ++h) {
          int dq = h * 4 + dg;
          float4 v = c4[dq];
          int dbase = dq * 4;
          cs[(dbase + 0) * KT + kl] = v.x;
          cs[(dbase + 1) * KT + kl] = v.y;
          cs[(dbase + 2) * KT + kl] = v.z;
          cs[(dbase + 3) * KT + kl] = v.w;
        }
      }
      __syncthreads();
      float acc[4][4];
#pragma unroll
      for (int i = 0; i < 4; ++i)
#pragma unroll
        for (int j = 0; j < 4; ++j) acc[i][j] = 0.0f;
#pragma unroll
      for (int d = 0; d < DT; ++d) {
        float4 xv = ((const float4*)(xs + (size_t)(dc * DT + d) * MP))[tp];
        float4 cv = ((const float4*)(cs + (size_t)d * KT))[tk];
        float xa[4] = {xv.x, xv.y, xv.z, xv.w};
        float ca[4] = {cv.x, cv.y, cv.z, cv.w};
#pragma unroll
        for (int i = 0; i < 4; ++i)
#pragma unroll
          for (int j = 0; j < 4; ++j) acc[i][j] = fmaf(xa[i], ca[j], acc[i][j]);
      }
#pragma unroll
      for (int i = 0; i < 4; ++i)
#pragma unroll
        for (int j = 0; j < 4; ++j) dacc[i][j] += (double)acc[i][j];
    }
#pragma unroll
    for (int j = 0; j < 4; ++j) {
      int k = k0 + tk * 4 + j;
      double c2v = c2[k];
#pragma unroll
      for (int i = 0; i < 4; ++i) {
        double s = c2v - 2.0 * dacc[i][j];
        if (s < best[i]) { best[i] = s; bestk[i] = k; }
      }
    }
  }
  __syncthreads();
  double* redv = (double*)cs;
  int* redk = (int*)xs;
  int* bk = (int*)xs + 1024;
#pragma unroll
  for (int i = 0; i < 4; ++i) {
    int p = tp * 4 + i;
    redv[tk * MP + p] = best[i];
    redk[tk * MP + p] = bestk[i];
  }
  __syncthreads();
  if (tid < MP) {
    int p = tid;
    double bv = redv[p]; int bkk = redk[p];
#pragma unroll
    for (int t = 1; t < 16; ++t) {
      double v = redv[t * MP + p]; int kk = redk[t * MP + p];
      if (v < bv || (v == bv && kk < bkk)) { bv = v; bkk = kk; }
    }
    bk[p] = bkk;
    idx_out[p0 + p] = bkk;
  }
  __syncthreads();
  float* orow = out + (size_t)p0 * KTOT;
  for (int l = tid; l < MP * KTOT; l += 256) {
    int p = l >> 9;
    int k = l & (KTOT - 1);
    orow[l] = (k == bk[p]) ? 1.0f : 0.0f;
  }
}

extern "C" void kernel_launch(void* const* d_in, const int* in_sizes, int n_in,
                              void* d_out, int out_size, void* d_ws, size_t ws_size,
                              hipStream_t stream) {
  const float* x = (const float*)d_in[0];
  const float* c = (const float*)d_in[1];
  float* out = (float*)d_out;
  float* outc = out + (size_t)NPTS * KTOT;

  char* ws = (char*)d_ws;

  if (ws_size >= WS_MAIN_NEED) {
    double* c2   = (double*)(ws + 0);
    u16* Ch      = (u16*)(ws + 4096);
    int* idx     = (int*)(ws + 528384);
    float* pv1   = (float*)(ws + 1052672);
    int* pkk     = (int*)(ws + 3149824);
    unsigned* pgg= (unsigned*)(ws + 5246976);
    float* sums  = (float*)(ws + 7344128);
    int* counts  = (int*)(ws + 7868416);
    int* flagcnt = (int*)(ws + 7870464);
    int* flaglist= (int*)(ws + 7870528);
    // overlays (dead after combine):
    int* offsets = (int*)(ws + 1052672);            // 513 ints, over pv1
    int* cursors = (int*)(ws + 1052672 + 4096);     // 512 ints, over pv1
    int* plist   = (int*)(ws + 5246976);            // 131072 ints, over pgg
    // out-buffer scratch (onehot rewrites out afterwards):
    float* cT    = (float*)((char*)out + 134217728);        // 512 KB

    hipMemsetAsync(sums, 0, (size_t)(KTOT * DIM + KTOT) * 4, stream);  // sums + counts
    hipMemsetAsync(flagcnt, 0, 64, stream);
    prep_c_kernel<<<KTOT, 64, 0, stream>>>(c, c2, Ch, cT);
    gemm_topk_kernel<<<4096, 256, 0, stream>>>(x, Ch, c2, pv1, pkk, pgg);
    combine_kernel<<<NPTS / 256, 256, 0, stream>>>(pv1, pkk, pgg, idx, flagcnt, flaglist, counts);
    full_refine_kernel<<<256, 256, 0, stream>>>(x, cT, c2, flagcnt, flaglist, idx, counts);
    pair_refine_kernel<<<256, 256, 0, stream>>>(x, c, c2, flagcnt, flaglist, idx, counts);
    onehot_kernel<<<NPTS / 32, 256, 0, stream>>>(idx, out);
    scan_kernel<<<1, 512, 0, stream>>>(counts, offsets, cursors);
    scatter_kernel<<<NPTS / 1024, 256, 0, stream>>>(idx, cursors, plist);
    gathersum_flat_kernel<<<NPTS / 32 / 4, 256, 0, stream>>>(x, plist, offsets, sums);
    ema_kernel<<<KTOT, DIM, 0, stream>>>(c, sums, counts, outc);
  } else {
    // round-1 fallback (ws >= 1.05 MB proven)
    double* c2  = (double*)ws;
    int* idx    = (int*)(ws + 4096);
    float* sums = (float*)(ws + 4096 + 524288);
    int* counts = (int*)(ws + 4096 + 524288 + 524288);
    hipMemsetAsync(sums, 0, (size_t)(KTOT * DIM + KTOT) * 4, stream);
    c2_kernel<<<KTOT, 64, 0, stream>>>(c, c2);
    assign_kernel_r1<<<NPTS / MP, 256, 0, stream>>>(x, c, c2, out, idx);
    sums_kernel<<<(KTOT / GB) * SLICES, 256, 0, stream>>>(x, idx, sums, counts);
    ema_kernel<<<KTOT, DIM, 0, stream>>>(c, sums, counts, outc);
  }
}

// Round 9
// 703.869 us; speedup vs baseline: 1.2009x; 1.1792x over previous
//
#include <hip/hip_runtime.h>
#include <hip/hip_fp16.h>

#define NPTS 131072   // B*S = 128*1024
#define DIM  256
#define KTOT 512
// f16 GEMM score error eps <= ~0.1 (validated: GAP 0.2 full-rescan rounds passed => 2*eps <= 0.2).
// Pair-check when exactly 2 candidates within GAP_FULL and gap < GAP_PAIR;
// full exact scan when >=3 candidates within GAP_FULL of the best.
#define GAP_PAIR 0.2f
#define GAP_FULL 0.4f

typedef unsigned short u16;
typedef _Float16 half8 __attribute__((ext_vector_type(8)));
typedef float floatx4 __attribute__((ext_vector_type(4)));

union F16U { _Float16 f; unsigned short u; };

// ---------------- ws layout (main path) ----------------
// 0        : c2 double[512]                    (4096)
// 4096     : Ch u16[512*256]                   (262144)
// 528384   : idx int[131072]                   (524288)
// 1052672  : pv1 float[4][131072]              (2097152)   | after combine: offsets int[513], cursors int[512]
// 3149824  : pkk int[4][131072]                (2097152)
// 5246976  : pgg uint[4][131072]               (2097152)   | after combine: plist int[131072]
// 7344128  : sums float[512*256]               (524288)
// 7868416  : counts int[512]                   (2048)
// 7870464  : flagcnt int[16]  ([0]=full,[1]=pair)  (64)
// 7870528  : flaglist int[131072]: full[0..32767], pairm[32768..], pairkk[65536..]
#define WS_MAIN_NEED 8394816u
// out-buffer scratch (rewritten by onehot at the end):
//   cT float[DIM][KTOT] at out+128MB   (512 KB) — transposed centroids, read only by full_refine

// ---------- shared helpers ----------
__device__ __forceinline__ void ins2(float v, int k, float& B, int& KB, float& S, int& KS) {
  if (v < B || (v == B && k < KB)) { S = B; KS = KB; B = v; KB = k; }
  else if (v < S || (v == S && k < KS)) { S = v; KS = k; }
}

// ---------- c2 in fp64 (fallback path) ----------
__global__ __launch_bounds__(64)
void c2_kernel(const float* __restrict__ c, double* __restrict__ c2) {
  int k = blockIdx.x;
  int lane = threadIdx.x;
  const float* row = c + (size_t)k * DIM;
  double s = 0.0;
#pragma unroll
  for (int r = 0; r < DIM / 64; ++r) {
    float v = row[r * 64 + lane];
    s += (double)v * (double)v;
  }
#pragma unroll
  for (int off = 32; off > 0; off >>= 1) s += __shfl_down(s, off);
  if (lane == 0) c2[k] = s;
}

// ---------- fused centroid prep: c2 (f64) + Ch (f16 swizzled) + cT (transpose) + flagcnt zero ----------
__global__ __launch_bounds__(64)
void prep_c_kernel(const float* __restrict__ c, double* __restrict__ c2,
                   u16* __restrict__ Ch, float* __restrict__ cT, int* __restrict__ flagcnt) {
  int k = blockIdx.x, lane = threadIdx.x;
  if (k == 0 && lane < 16) flagcnt[lane] = 0;
  const float* row = c + (size_t)k * DIM;
  float4 v = ((const float4*)row)[lane];   // dims lane*4 .. lane*4+3
  double s = (double)v.x * v.x + (double)v.y * v.y + (double)v.z * v.z + (double)v.w * v.w;
#pragma unroll
  for (int off = 32; off > 0; off >>= 1) s += __shfl_down(s, off);
  if (lane == 0) c2[k] = s;
  cT[(size_t)(lane * 4 + 0) * KTOT + k] = v.x;
  cT[(size_t)(lane * 4 + 1) * KTOT + k] = v.y;
  cT[(size_t)(lane * 4 + 2) * KTOT + k] = v.z;
  cT[(size_t)(lane * 4 + 3) * KTOT + k] = v.w;
  // Ch swizzled: chunk cg = lane>>1, half h = lane&1 covers dims lane*4..+3
  int cg = lane >> 1, h = lane & 1;
  int kc = cg >> 3, cc = cg & 7;
  union { _Float16 hh[4]; ushort4 u; } cvt;
  cvt.hh[0] = (_Float16)v.x; cvt.hh[1] = (_Float16)v.y;
  cvt.hh[2] = (_Float16)v.z; cvt.hh[3] = (_Float16)v.w;
  *(ushort4*)(Ch + (size_t)k * DIM + kc * 64 + (size_t)(cc ^ (k & 7)) * 8 + h * 4) = cvt.u;
}

// ---------- MFMA f16 GEMM + shuffle-free LDS-scan epilogue (top-2-kv + third value) ----------
__device__ __forceinline__ void load_lds16(const void* g, void* l) {
  __builtin_amdgcn_global_load_lds((const __attribute__((address_space(1))) void*)g,
                                   (__attribute__((address_space(3))) void*)l, 16, 0, 0);
}

__global__ __launch_bounds__(256)
void gemm_topk_kernel(const float* __restrict__ x, const u16* __restrict__ Ch,
                      const double* __restrict__ c2,
                      float* __restrict__ pv1, int* __restrict__ pkk, unsigned* __restrict__ pgg) {
  // 33792 B: A/B staging (32 KB) overlaid with score buffer 64x132 f32
  __shared__ __align__(16) unsigned char smem[33792];
  __shared__ float rB[128], rS[128], rT[128];
  __shared__ int rKB[128], rKS[128];
  u16* Ah = (u16*)smem;          // [128][64]
  u16* Bh = Ah + 8192;
  float* sc = (float*)smem;      // [64][132]

  const int tid = threadIdx.x;
  const int bx = blockIdx.x;
  // XCD-aware swizzle: 4 n-blocks sharing an A-tile land on the same XCD
  const int nblk = (bx >> 3) & 3;
  const int mblk = (bx & 7) + ((bx >> 5) << 3);
  const int m0 = mblk * 128, n0 = nblk * 128;
  const int w = tid >> 6, lane = tid & 63;
  const int wm = (w & 1) * 64, wn = (w >> 1) * 64;
  const int lm = lane & 15, quad = lane >> 4;

  floatx4 acc[4][4] = {};

  for (int kc = 0; kc < 4; ++kc) {
    const int k0 = kc * 64;
    __syncthreads();
#pragma unroll
    for (int i = 0; i < 4; ++i) {
      int s = i * 256 + tid;
      int row = s >> 3, pos = s & 7;
      size_t go = (size_t)(n0 + row) * DIM + k0 + pos * 8;
      load_lds16(Ch + go, Bh + (size_t)s * 8);
    }
#pragma unroll
    for (int i = 0; i < 4; ++i) {
      int s = i * 256 + tid;
      int row = s >> 3, kg = s & 7;
      const float4* gx = (const float4*)(x + (size_t)(m0 + row) * DIM + k0 + kg * 8);
      float4 f0 = gx[0], f1 = gx[1];
      float fv[8] = {f0.x, f0.y, f0.z, f0.w, f1.x, f1.y, f1.z, f1.w};
      half8 hv;
#pragma unroll
      for (int e = 0; e < 8; ++e) hv[e] = (_Float16)fv[e];
      int pos = kg ^ (row & 7);
      *(half8*)(Ah + (size_t)row * 64 + pos * 8) = hv;
    }
    __syncthreads();

#pragma unroll
    for (int s = 0; s < 2; ++s) {
      half8 ah[4], bh[4];
#pragma unroll
      for (int t = 0; t < 4; ++t) {
        int m = wm + t * 16 + lm;
        int pa = ((s * 4 + quad) ^ (m & 7)) * 8;
        ah[t] = *(const half8*)(Ah + (size_t)m * 64 + pa);
        int n = wn + t * 16 + lm;
        int pb = ((s * 4 + quad) ^ (n & 7)) * 8;
        bh[t] = *(const half8*)(Bh + (size_t)n * 64 + pb);
      }
#pragma unroll
      for (int mt = 0; mt < 4; ++mt)
#pragma unroll
        for (int nt = 0; nt < 4; ++nt)
          acc[mt][nt] = __builtin_amdgcn_mfma_f32_16x16x32_f16(ah[mt], bh[nt], acc[mt][nt], 0, 0, 0);
    }
  }

  float c2f[4];
#pragma unroll
  for (int nt = 0; nt < 4; ++nt) c2f[nt] = (float)c2[n0 + wn + nt * 16 + lm];

  // ---- epilogue: two 64-row halves; scores to LDS; scalar scan (NO shuffles) ----
  for (int half = 0; half < 2; ++half) {
    __syncthreads();   // AB frag reads done (half 0) / prev merge reads done (half 1)
#pragma unroll
    for (int mt2 = 0; mt2 < 2; ++mt2) {
      int mt = half * 2 + mt2;
      int hrow0 = (wm >> 1) + mt2 * 16 + quad * 4;
#pragma unroll
      for (int r = 0; r < 4; ++r)
#pragma unroll
        for (int nt = 0; nt < 4; ++nt)
          sc[(hrow0 + r) * 132 + wn + nt * 16 + lm] = c2f[nt] - 2.0f * acc[mt][nt][r];
    }
    __syncthreads();
    // scan: 4 threads/row over 64 rows; each scans 32 cols ascending (tie -> lower n)
    {
      int hrow = tid >> 2, seg = tid & 3;
      float B = 1e30f, S = 1e30f, T = 1e30f;
      int KB = -1, KS = -1;
      const float4* rp = (const float4*)(sc + hrow * 132 + seg * 32);
#pragma unroll
      for (int j = 0; j < 8; ++j) {
        float4 v4 = rp[j];
        float va[4] = {v4.x, v4.y, v4.z, v4.w};
#pragma unroll
        for (int e = 0; e < 4; ++e) {
          float v = va[e];
          int n = seg * 32 + j * 4 + e;
          if (v < B) { T = S; S = B; KS = KB; B = v; KB = n; }
          else if (v < S) { T = S; S = v; KS = n; }
          else if (v < T) T = v;
        }
      }
      __syncthreads();
      // stash seg results into dead score area
      float* sb = sc;
      int base = (hrow * 4 + seg) * 5;
      sb[base + 0] = B;
      sb[base + 1] = __int_as_float(KB);
      sb[base + 2] = S;
      sb[base + 3] = __int_as_float(KS);
      sb[base + 4] = T;
    }
    __syncthreads();
    if (tid < 64) {
      float* sb = sc;
      float B = 1e30f, S = 1e30f, T = 1e30f;
      int KB = -1, KS = -1;
#pragma unroll
      for (int s2 = 0; s2 < 4; ++s2) {     // ascending seg = ascending n: ties keep lower key
        const float* e = sb + (tid * 4 + s2) * 5;
        float b2 = e[0]; int kb2 = __float_as_int(e[1]);
        float s3 = e[2]; int ks2 = __float_as_int(e[3]);
        float t2 = e[4];
        if (b2 < B) { T = S; S = B; KS = KB; B = b2; KB = kb2; }
        else if (b2 < S) { T = S; S = b2; KS = kb2; }
        else if (b2 < T) T = b2;
        if (s3 < S) { T = S; S = s3; KS = ks2; }   // s3 >= b2 >= B: never displaces B
        else if (s3 < T) T = s3;
        if (t2 < T) T = t2;                        // seg third can only land in T
      }
      int m = (tid < 32 ? tid : tid + 32) + half * 32;
      rB[m] = B; rKB[m] = KB; rS[m] = S; rKS[m] = KS; rT[m] = T;
    }
  }
  __syncthreads();
  if (tid < 128) {
    float B = rB[tid], S = rS[tid], T = rT[tid];
    int m = m0 + tid;
    F16U g1; g1.f = (_Float16)(S - B);
    F16U g2; g2.f = (_Float16)(T - B);
    pv1[(size_t)nblk * NPTS + m] = B;
    pkk[(size_t)nblk * NPTS + m] = (rKB[tid] + n0) | ((rKS[tid] + n0) << 16);
    pgg[(size_t)nblk * NPTS + m] = (unsigned)g1.u | ((unsigned)g2.u << 16);
  }
}

// ---------- merge 4 n-block partials -> idx + hist + pair/full flag lists ----------
__global__ __launch_bounds__(256)
void combine_kernel(const float* __restrict__ pv1, const int* __restrict__ pkk,
                    const unsigned* __restrict__ pgg, int* __restrict__ idx,
                    int* __restrict__ flagcnt, int* __restrict__ flaglist,
                    int* __restrict__ counts) {
  __shared__ int h[KTOT];
  int t = threadIdx.x;
#pragma unroll
  for (int i = 0; i < KTOT / 256; ++i) h[i * 256 + t] = 0;
  __syncthreads();
  int m = blockIdx.x * 256 + t;
  float B = 1e30f, S = 1e30f;
  int KB = 0x7fffffff, KS = 0x7fffffff;
  float bb[4], ss[4], tt[4];
#pragma unroll
  for (int b = 0; b < 4; ++b) {     // ascending b = ascending k
    float bv = pv1[(size_t)b * NPTS + m];
    int kk = pkk[(size_t)b * NPTS + m];
    unsigned gg = pgg[(size_t)b * NPTS + m];
    int kb_ = kk & 0xffff, ks_ = (kk >> 16) & 0xffff;
    F16U u1; u1.u = (unsigned short)(gg & 0xffffu);
    F16U u2; u2.u = (unsigned short)(gg >> 16);
    float sv = bv + (float)u1.f, tv = bv + (float)u2.f;
    bb[b] = bv; ss[b] = sv; tt[b] = tv;
    ins2(bv, kb_, B, KB, S, KS);
    ins2(sv, ks_, B, KB, S, KS);
  }
  idx[m] = KB;
  atomicAdd(&h[KB], 1);
  float thr = B + GAP_FULL;
  int tot = 0;
#pragma unroll
  for (int b = 0; b < 4; ++b)
    tot += ((bb[b] < thr) ? 1 : 0) + ((ss[b] < thr) ? 1 : 0) + ((tt[b] < thr) ? 1 : 0);
  if (tot >= 3) {
    int p = atomicAdd(&flagcnt[0], 1);
    if (p < 32768) flaglist[p] = m;                       // full exact scan
  } else if (tot == 2 && (S - B) < GAP_PAIR) {
    int p = atomicAdd(&flagcnt[1], 1);
    if (p < 32768) {
      flaglist[32768 + p] = m;                            // pair check
      flaglist[65536 + p] = KB | (KS << 16);
    }
  }
  __syncthreads();
#pragma unroll
  for (int i = 0; i < KTOT / 256; ++i) {
    int v = h[i * 256 + t];
    if (v) atomicAdd(&counts[i * 256 + t], v);
  }
}

// ---------- exact f64 check of the two candidates (one wave per point) ----------
__global__ __launch_bounds__(256)
void pair_refine_kernel(const float* __restrict__ x, const float* __restrict__ c,
                        const double* __restrict__ c2, const int* __restrict__ flagcnt,
                        const int* __restrict__ flaglist, int* __restrict__ idx,
                        int* __restrict__ counts) {
  int cnt = *(volatile const int*)(flagcnt + 1);
  const int w = threadIdx.x >> 6, lane = threadIdx.x & 63;
  for (int e = blockIdx.x * 4 + w; e < cnt; e += gridDim.x * 4) {
    int m = flaglist[32768 + e];
    int kk = flaglist[65536 + e];
    int ka = kk & 0xffff, kb = (kk >> 16) & 0xffff;
    float4 xv = ((const float4*)(x + (size_t)m * DIM))[lane];
    float4 av = ((const float4*)(c + (size_t)ka * DIM))[lane];
    float4 bv = ((const float4*)(c + (size_t)kb * DIM))[lane];
    float fa = fmaf(xv.x, av.x, fmaf(xv.y, av.y, fmaf(xv.z, av.z, xv.w * av.w)));
    float fb = fmaf(xv.x, bv.x, fmaf(xv.y, bv.y, fmaf(xv.z, bv.z, xv.w * bv.w)));
    double da = (double)fa, db = (double)fb;
#pragma unroll
    for (int off = 32; off > 0; off >>= 1) {
      da += __shfl_down(da, off);
      db += __shfl_down(db, off);
    }
    if (lane == 0) {
      double sa = c2[ka] - 2.0 * da, sb = c2[kb] - 2.0 * db;
      int wk = (sb < sa || (sb == sa && kb < ka)) ? kb : ka;
      if (wk != ka) {      // idx[m] == ka (tentative best)
        idx[m] = wk;
        atomicSub(&counts[ka], 1);
        atomicAdd(&counts[wk], 1);
      }
    }
  }
}

// ---------- full exact scan of rare >=3-candidate points (coalesced vs cT) ----------
__global__ __launch_bounds__(256)
void full_refine_kernel(const float* __restrict__ x, const float* __restrict__ cT,
                        const double* __restrict__ c2, const int* __restrict__ flagcnt,
                        const int* __restrict__ flaglist, int* __restrict__ idx,
                        int* __restrict__ counts) {
  __shared__ __align__(16) float xs[DIM];
  __shared__ double rv[256];
  __shared__ int rk[256];
  int cnt = *(volatile const int*)flagcnt;
  const int ka = threadIdx.x, kb = threadIdx.x + 256;
  for (int i = blockIdx.x; i < cnt; i += gridDim.x) {
    __syncthreads();
    int m = flaglist[i];
    if (threadIdx.x < 64)
      ((float4*)xs)[threadIdx.x] = ((const float4*)(x + (size_t)m * DIM))[threadIdx.x];
    __syncthreads();
    double da = 0.0, db = 0.0;
#pragma unroll
    for (int dc = 0; dc < 8; ++dc) {
      float fa = 0.0f, fb = 0.0f;
#pragma unroll
      for (int d4 = 0; d4 < 8; ++d4) {
        float4 xv = ((const float4*)xs)[dc * 8 + d4];
        const float* ct0 = cT + (size_t)(dc * 32 + d4 * 4) * KTOT;
        fa = fmaf(xv.x, ct0[ka], fa);            fb = fmaf(xv.x, ct0[kb], fb);
        fa = fmaf(xv.y, ct0[KTOT + ka], fa);     fb = fmaf(xv.y, ct0[KTOT + kb], fb);
        fa = fmaf(xv.z, ct0[2 * KTOT + ka], fa); fb = fmaf(xv.z, ct0[2 * KTOT + kb], fb);
        fa = fmaf(xv.w, ct0[3 * KTOT + ka], fa); fb = fmaf(xv.w, ct0[3 * KTOT + kb], fb);
      }
      da += (double)fa; db += (double)fb;
    }
    double sa = c2[ka] - 2.0 * da, sb = c2[kb] - 2.0 * db;
    double bestv; int bestk;
    if (sa <= sb) { bestv = sa; bestk = ka; }
    else          { bestv = sb; bestk = kb; }
    rv[threadIdx.x] = bestv; rk[threadIdx.x] = bestk;
    __syncthreads();
    for (int off = 128; off > 0; off >>= 1) {
      if (threadIdx.x < off) {
        double v = rv[threadIdx.x + off]; int kk = rk[threadIdx.x + off];
        if (v < rv[threadIdx.x] || (v == rv[threadIdx.x] && kk < rk[threadIdx.x])) {
          rv[threadIdx.x] = v; rk[threadIdx.x] = kk;
        }
      }
      __syncthreads();
    }
    if (threadIdx.x == 0) {
      int bk = rk[0];
      int old = idx[m];
      if (bk != old) {
        idx[m] = bk;
        atomicSub(&counts[old], 1);
        atomicAdd(&counts[bk], 1);
      }
    }
  }
}

// ---------- one-hot write ----------
__global__ __launch_bounds__(256)
void onehot_kernel(const int* __restrict__ idx, float* __restrict__ out) {
  __shared__ int bk[32];
  int b = blockIdx.x;
  if (threadIdx.x < 32) bk[threadIdx.x] = idx[b * 32 + threadIdx.x];
  __syncthreads();
  float4* o = (float4*)(out + (size_t)b * 32 * KTOT);
#pragma unroll
  for (int j = 0; j < 16; ++j) {
    int f4 = j * 256 + threadIdx.x;
    int p = f4 >> 7;
    int n4 = (f4 & 127) * 4;
    int k = bk[p];
    float4 v;
    v.x = (k == n4 + 0) ? 1.0f : 0.0f;
    v.y = (k == n4 + 1) ? 1.0f : 0.0f;
    v.z = (k == n4 + 2) ? 1.0f : 0.0f;
    v.w = (k == n4 + 3) ? 1.0f : 0.0f;
    o[f4] = v;
  }
}

// ================= counting-sort sums pipeline =================
__global__ __launch_bounds__(512)
void scan_kernel(const int* __restrict__ counts, int* __restrict__ offsets,
                 int* __restrict__ cursors) {
  __shared__ int s[KTOT];
  int t = threadIdx.x;
  int mine = counts[t];
  s[t] = mine;
  __syncthreads();
  for (int off = 1; off < KTOT; off <<= 1) {
    int v = (t >= off) ? s[t - off] : 0;
    __syncthreads();
    s[t] += v;
    __syncthreads();
  }
  int excl = s[t] - mine;
  offsets[t] = excl;
  cursors[t] = excl;
  if (t == KTOT - 1) offsets[KTOT] = s[t];
}

__global__ __launch_bounds__(256)
void scatter_kernel(const int* __restrict__ idx, int* __restrict__ cursors,
                    int* __restrict__ plist) {
  int base = blockIdx.x * 1024 + threadIdx.x;
#pragma unroll
  for (int j = 0; j < 4; ++j) {
    int n = base + j * 256;
    int k = idx[n];
    int pos = atomicAdd(&cursors[k], 1);
    plist[pos] = n;
  }
}

// gathersum_flat: skew-proof — every wave owns 32 consecutive sorted positions.
__global__ __launch_bounds__(256)
void gathersum_flat_kernel(const float* __restrict__ x, const int* __restrict__ plist,
                           const int* __restrict__ offsets, float* __restrict__ sums) {
  __shared__ int offs[KTOT + 1];
  for (int t = threadIdx.x; t < KTOT + 1; t += 256) offs[t] = offsets[t];
  __syncthreads();
  const int w = threadIdx.x >> 6, lane = threadIdx.x & 63;
  const int wid = blockIdx.x * 4 + w;
  const int p0 = wid * 32, p1 = p0 + 32;

  int lo = 0, hi = KTOT;
  while (hi - lo > 1) { int mid = (lo + hi) >> 1; if (offs[mid] <= p0) lo = mid; else hi = mid; }
  int k = lo;

  float4 acc = make_float4(0.f, 0.f, 0.f, 0.f);
  bool any = false;
#pragma unroll 4
  for (int i = p0; i < p1; ++i) {
    while (i >= offs[k + 1]) {
      if (any) {
        float* dst = sums + (size_t)k * DIM + lane * 4;
        atomicAdd(dst + 0, acc.x); atomicAdd(dst + 1, acc.y);
        atomicAdd(dst + 2, acc.z); atomicAdd(dst + 3, acc.w);
        acc = make_float4(0.f, 0.f, 0.f, 0.f);
        any = false;
      }
      ++k;
    }
    int pid = plist[i];
    float4 v = ((const float4*)x)[(size_t)pid * 64 + lane];
    acc.x += v.x; acc.y += v.y; acc.z += v.z; acc.w += v.w;
    any = true;
  }
  if (any) {
    float* dst = sums + (size_t)k * DIM + lane * 4;
    atomicAdd(dst + 0, acc.x); atomicAdd(dst + 1, acc.y);
    atomicAdd(dst + 2, acc.z); atomicAdd(dst + 3, acc.w);
  }
}

__global__ __launch_bounds__(256)
void ema_kernel(const float* __restrict__ c, const float* __restrict__ sums,
                const int* __restrict__ counts, float* __restrict__ outc) {
  int k = blockIdx.x;
  int d = threadIdx.x;
  float cnt = (float)counts[k];
  size_t o = (size_t)k * DIM + d;
  float nc = sums[o] / cnt;
  outc[o] = 0.9f * c[o] + 0.1f * nc;
}

// ---------- round-1 ballot sums (fallback path only) ----------
#define GB 4
#define SLICES 8
__global__ __launch_bounds__(256)
void sums_kernel(const float* __restrict__ x, const int* __restrict__ idx,
                 float* __restrict__ sums, int* __restrict__ counts) {
  const int groups = KTOT / GB;
  const int group = blockIdx.x % groups;
  const int slice = blockIdx.x / groups;
  const int kg0 = group * GB;
  const int tid = threadIdx.x;
  const int lane = tid & 63;
  const int w = tid >> 6;
  const int per_slice = NPTS / SLICES;
  const int nbeg = slice * per_slice;

  float4 acc[GB];
  int cnt[GB];
#pragma unroll
  for (int j = 0; j < GB; ++j) { acc[j] = make_float4(0.f, 0.f, 0.f, 0.f); cnt[j] = 0; }

  for (int it = 0; it < per_slice; it += 256) {
    int n = nbeg + it + tid;
    int k = idx[n];
#pragma unroll
    for (int j = 0; j < GB; ++j) {
      unsigned long long m = __ballot(k == kg0 + j);
      while (m) {
        int src = __ffsll((unsigned long long)m) - 1;
        int nn = __shfl(n, src);
        float4 v = ((const float4*)(x + (size_t)nn * DIM))[lane];
        acc[j].x += v.x; acc[j].y += v.y; acc[j].z += v.z; acc[j].w += v.w;
        cnt[j]++;
        m &= (m - 1);
      }
    }
  }

  __shared__ __align__(16) float lacc[4][GB][DIM];
  __shared__ int lcnt[4][GB];
#pragma unroll
  for (int j = 0; j < GB; ++j) ((float4*)&lacc[w][j][0])[lane] = acc[j];
  if (lane == 0) {
#pragma unroll
    for (int j = 0; j < GB; ++j) lcnt[w][j] = cnt[j];
  }
  __syncthreads();
#pragma unroll
  for (int j = 0; j < GB; ++j) {
    float s = lacc[0][j][tid] + lacc[1][j][tid] + lacc[2][j][tid] + lacc[3][j][tid];
    atomicAdd(&sums[(size_t)(kg0 + j) * DIM + tid], s);
  }
  if (tid < GB) {
    int ct = lcnt[0][tid] + lcnt[1][tid] + lcnt[2][tid] + lcnt[3][tid];
    atomicAdd(&counts[kg0 + tid], ct);
  }
}

// ================= round-1 fallback assign (if ws too small) =================
#define MP 64
#define KT 64
#define DT 32
__global__ __launch_bounds__(256, 2)
void assign_kernel_r1(const float* __restrict__ x, const float* __restrict__ c,
                      const double* __restrict__ c2, float* __restrict__ out,
                      int* __restrict__ idx_out) {
  __shared__ __align__(16) float xs[DIM * MP];
  __shared__ __align__(16) float cs[DT * KT];
  const int tid = threadIdx.x;
  const int p0 = blockIdx.x * MP;
  const int tp = tid & 15;
  const int tk = tid >> 4;
  {
    const int p = tid >> 2;
    const int dg = tid & 3;
    const float4* x4 = (const float4*)(x + (size_t)(p0 + p) * DIM);
#pragma unroll
    for (int r = 0; r < 16; ++r) {
      int d4 = r * 4 + dg;
      float4 v = x4[d4];
      int dbase = d4 * 4;
      xs[(dbase + 0) * MP + p] = v.x;
      xs[(dbase + 1) * MP + p] = v.y;
      xs[(dbase + 2) * MP + p] = v.z;
      xs[(dbase + 3) * MP + p] = v.w;
    }
  }
  double best[4]; int bestk[4];
#pragma unroll
  for (int i = 0; i < 4; ++i) { best[i] = 1e300; bestk[i] = 0; }
  for (int kc = 0; kc < KTOT / KT; ++kc) {
    const int k0 = kc * KT;
    double dacc[4][4];
#pragma unroll
    for (int i = 0; i < 4; ++i)
#pragma unroll
      for (int j = 0; j < 4; ++j) dacc[i][j] = 0.0;
    for (int dc = 0; dc < DIM / DT; ++dc) {
      __syncthreads();
      {
        const int kl = tid >> 2;
        const int dg = tid & 3;
        const float4* c4 = (const float4*)(c + (size_t)(k0 + kl) * DIM + dc * DT);
#pragma unroll
        for (int h = 0; h < 2; ++h) {
          int dq = h * 4 + dg;
          float4 v = c4[dq];
          int dbase = dq * 4;
          cs[(dbase + 0) * KT + kl] = v.x;
          cs[(dbase + 1) * KT + kl] = v.y;
          cs[(dbase + 2) * KT + kl] = v.z;
          cs[(dbase + 3) * KT + kl] = v.w;
        }
      }
      __syncthreads();
      float acc[4][4];
#pragma unroll
      for (int i = 0; i < 4; ++i)
#pragma unroll
        for (int j = 0; j < 4; ++j) acc[i][j] = 0.0f;
#pragma unroll
      for (int d = 0; d < DT; ++d) {
        float4 xv = ((const float4*)(xs + (size_t)(dc * DT + d) * MP))[tp];
        float4 cv = ((const float4*)(cs + (size_t)d * KT))[tk];
        float xa[4] = {xv.x, xv.y, xv.z, xv.w};
        float ca[4] = {cv.x, cv.y, cv.z, cv.w};
#pragma unroll
        for (int i = 0; i < 4; ++i)
#pragma unroll
          for (int j = 0; j < 4; ++j) acc[i][j] = fmaf(xa[i], ca[j], acc[i][j]);
      }
#pragma unroll
      for (int i = 0; i < 4; ++i)
#pragma unroll
        for (int j = 0; j < 4; ++j) dacc[i][j] += (double)acc[i][j];
    }
#pragma unroll
    for (int j = 0; j < 4; ++j) {
      int k = k0 + tk * 4 + j;
      double c2v = c2[k];
#pragma unroll
      for (int i = 0; i < 4; ++i) {
        double s = c2v - 2.0 * dacc[i][j];
        if (s < best[i]) { best[i] = s; bestk[i] = k; }
      }
    }
  }
  __syncthreads();
  double* redv = (double*)cs;
  int* redk = (int*)xs;
  int* bk = (int*)xs + 1024;
#pragma unroll
  for (int i = 0; i < 4; ++i) {
    int p = tp * 4 + i;
    redv[tk * MP + p] = best[i];
    redk[tk * MP + p] = bestk[i];
  }
  __syncthreads();
  if (tid < MP) {
    int p = tid;
    double bv = redv[p]; int bkk = redk[p];
#pragma unroll
    for (int t = 1; t < 16; ++t) {
      double v = redv[t * MP + p]; int kk = redk[t * MP + p];
      if (v < bv || (v == bv && kk < bkk)) { bv = v; bkk = kk; }
    }
    bk[p] = bkk;
    idx_out[p0 + p] = bkk;
  }
  __syncthreads();
  float* orow = out + (size_t)p0 * KTOT;
  for (int l = tid; l < MP * KTOT; l += 256) {
    int p = l >> 9;
    int k = l & (KTOT - 1);
    orow[l] = (k == bk[p]) ? 1.0f : 0.0f;
  }
}

extern "C" void kernel_launch(void* const* d_in, const int* in_sizes, int n_in,
                              void* d_out, int out_size, void* d_ws, size_t ws_size,
                              hipStream_t stream) {
  const float* x = (const float*)d_in[0];
  const float* c = (const float*)d_in[1];
  float* out = (float*)d_out;
  float* outc = out + (size_t)NPTS * KTOT;

  char* ws = (char*)d_ws;

  if (ws_size >= WS_MAIN_NEED) {
    double* c2   = (double*)(ws + 0);
    u16* Ch      = (u16*)(ws + 4096);
    int* idx     = (int*)(ws + 528384);
    float* pv1   = (float*)(ws + 1052672);
    int* pkk     = (int*)(ws + 3149824);
    unsigned* pgg= (unsigned*)(ws + 5246976);
    float* sums  = (float*)(ws + 7344128);
    int* counts  = (int*)(ws + 7868416);
    int* flagcnt = (int*)(ws + 7870464);
    int* flaglist= (int*)(ws + 7870528);
    // overlays (dead after combine):
    int* offsets = (int*)(ws + 1052672);            // 513 ints, over pv1
    int* cursors = (int*)(ws + 1052672 + 4096);     // 512 ints, over pv1
    int* plist   = (int*)(ws + 5246976);            // 131072 ints, over pgg
    // out-buffer scratch (onehot rewrites out afterwards):
    float* cT    = (float*)((char*)out + 134217728);        // 512 KB

    hipMemsetAsync(sums, 0, (size_t)(KTOT * DIM + KTOT) * 4, stream);  // sums + counts
    prep_c_kernel<<<KTOT, 64, 0, stream>>>(c, c2, Ch, cT, flagcnt);
    gemm_topk_kernel<<<4096, 256, 0, stream>>>(x, Ch, c2, pv1, pkk, pgg);
    combine_kernel<<<NPTS / 256, 256, 0, stream>>>(pv1, pkk, pgg, idx, flagcnt, flaglist, counts);
    full_refine_kernel<<<256, 256, 0, stream>>>(x, cT, c2, flagcnt, flaglist, idx, counts);
    pair_refine_kernel<<<256, 256, 0, stream>>>(x, c, c2, flagcnt, flaglist, idx, counts);
    onehot_kernel<<<NPTS / 32, 256, 0, stream>>>(idx, out);
    scan_kernel<<<1, 512, 0, stream>>>(counts, offsets, cursors);
    scatter_kernel<<<NPTS / 1024, 256, 0, stream>>>(idx, cursors, plist);
    gathersum_flat_kernel<<<NPTS / 32 / 4, 256, 0, stream>>>(x, plist, offsets, sums);
    ema_kernel<<<KTOT, DIM, 0, stream>>>(c, sums, counts, outc);
  } else {
    // round-1 fallback (ws >= 1.05 MB proven)
    double* c2  = (double*)ws;
    int* idx    = (int*)(ws + 4096);
    float* sums = (float*)(ws + 4096 + 524288);
    int* counts = (int*)(ws + 4096 + 524288 + 524288);
    hipMemsetAsync(sums, 0, (size_t)(KTOT * DIM + KTOT) * 4, stream);
    c2_kernel<<<KTOT, 64, 0, stream>>>(c, c2);
    assign_kernel_r1<<<NPTS / MP, 256, 0, stream>>>(x, c, c2, out, idx);
    sums_kernel<<<(KTOT / GB) * SLICES, 256, 0, stream>>>(x, idx, sums, counts);
    ema_kernel<<<KTOT, DIM, 0, stream>>>(c, sums, counts, outc);
  }
}